// Round 1
// baseline (1637.213 us; speedup 1.0000x reference)
//
#include <hip/hip_runtime.h>
#include <hip/hip_bf16.h>

// MoE FFN: B=4 T=2048 D=1024 F=4096 E=8 top-2, fp32 in/out.
// Strategy: fp32 router -> expert buckets -> bf16 MFMA grouped GEMMs
// (stage A: x@w1, x@w3 fused SwiGLU -> h; stage B: h@w2 -> atomicAdd out).

#define NTOK 8192
#define DMODEL 1024
#define FDIM 4096
#define NEXP 8

typedef __attribute__((ext_vector_type(8))) short s8v;   // 8 x bf16 (4 VGPR)
typedef __attribute__((ext_vector_type(4))) float f4v;   // MFMA accumulator

__device__ __forceinline__ int imin(int a, int b){ return a < b ? a : b; }

// fp32 -> bf16 round-to-nearest-even
__device__ __forceinline__ unsigned short f2b(float f){
  union { float f; unsigned u; } v; v.f = f;
  unsigned r = v.u + 0x7fffu + ((v.u >> 16) & 1u);
  return (unsigned short)(r >> 16);
}

__device__ __forceinline__ f4v mfma16(s8v a, s8v b, f4v c){
  return __builtin_amdgcn_mfma_f32_16x16x32_bf16(a, b, c, 0, 0, 0);
}

// async global->LDS, 16B/lane; LDS dest = wave-uniform base + lane*16
#define GLDS16(gp, lp) __builtin_amdgcn_global_load_lds(                      \
    (const __attribute__((address_space(1))) void*)(gp),                      \
    (__attribute__((address_space(3))) void*)(lp), 16, 0, 0)

// ---------------- fp32 -> bf16 elementwise (x) ----------------
__global__ void k_cvt(const float4* __restrict__ in, ushort4* __restrict__ out, int n4){
  int i = blockIdx.x * blockDim.x + threadIdx.x;
  int st = gridDim.x * blockDim.x;
  for(; i < n4; i += st){
    float4 v = in[i];
    ushort4 o;
    o.x = f2b(v.x); o.y = f2b(v.y); o.z = f2b(v.z); o.w = f2b(v.w);
    out[i] = o;
  }
}

// ---------------- fp32 [e][R][C] -> bf16 [e][C][R] transpose ----------------
__global__ void k_tr(const float* __restrict__ in, unsigned short* __restrict__ out,
                     int R, int C){
  __shared__ float tile[32][33];
  const float* src = in + (size_t)blockIdx.z * R * C;
  unsigned short* dst = out + (size_t)blockIdx.z * R * C;
  int bx = blockIdx.x * 32, by = blockIdx.y * 32;
  int tx = threadIdx.x & 31, ty = threadIdx.x >> 5;
  #pragma unroll
  for(int i = 0; i < 32; i += 8)
    tile[ty + i][tx] = src[(size_t)(by + ty + i) * C + bx + tx];
  __syncthreads();
  #pragma unroll
  for(int i = 0; i < 32; i += 8)
    dst[(size_t)(bx + ty + i) * R + by + tx] = f2b(tile[tx][ty + i]);
}

// ---------------- router: fp32 logits -> softmax -> top2 -> renorm ----------------
__global__ void k_router(const float* __restrict__ x, const float* __restrict__ gw,
                         int* __restrict__ route_e, float* __restrict__ route_w,
                         int* __restrict__ counts){
  int lane = threadIdx.x & 63;
  int t = blockIdx.x * 4 + (threadIdx.x >> 6);   // one wave per token
  const float* xr = x + (size_t)t * DMODEL;
  float acc[NEXP];
  #pragma unroll
  for(int e = 0; e < NEXP; e++) acc[e] = 0.f;
  for(int d = lane; d < DMODEL; d += 64){
    float xv = xr[d];
    const float* g = gw + d * NEXP;
    #pragma unroll
    for(int e = 0; e < NEXP; e++) acc[e] += xv * g[e];
  }
  #pragma unroll
  for(int off = 32; off > 0; off >>= 1){
    #pragma unroll
    for(int e = 0; e < NEXP; e++) acc[e] += __shfl_down(acc[e], off, 64);
  }
  if(lane == 0){
    float mx = acc[0];
    #pragma unroll
    for(int e = 1; e < NEXP; e++) mx = fmaxf(mx, acc[e]);
    float p[NEXP];
    #pragma unroll
    for(int e = 0; e < NEXP; e++) p[e] = expf(acc[e] - mx);
    int i0 = 0;
    #pragma unroll
    for(int e = 1; e < NEXP; e++) if(p[e] > p[i0]) i0 = e;     // first-max (jax tie rule)
    int i1 = (i0 == 0) ? 1 : 0;
    #pragma unroll
    for(int e = 0; e < NEXP; e++) if(e != i0 && p[e] > p[i1]) i1 = e;
    float inv = 1.f / (p[i0] + p[i1]);           // softmax denom cancels in ratio
    route_e[2*t]   = i0; route_e[2*t+1] = i1;
    route_w[2*t]   = p[i0] * inv;
    route_w[2*t+1] = p[i1] * inv;
    atomicAdd(&counts[i0], 1); atomicAdd(&counts[i1], 1);
  }
}

__global__ void k_scan(const int* __restrict__ counts, int* __restrict__ offsets,
                       int* __restrict__ cursor){
  if(threadIdx.x == 0){
    int o = 0;
    for(int e = 0; e < NEXP; e++){ offsets[e] = o; o += counts[e]; cursor[e] = 0; }
    offsets[NEXP] = o;
  }
}

__global__ void k_fill(const int* __restrict__ route_e, const float* __restrict__ route_w,
                       const int* __restrict__ offsets, int* __restrict__ cursor,
                       int* __restrict__ pair_tok, float* __restrict__ pair_wt){
  int t = blockIdx.x * blockDim.x + threadIdx.x;
  if(t >= NTOK) return;
  #pragma unroll
  for(int k = 0; k < 2; k++){
    int e = route_e[2*t + k];
    int pos = atomicAdd(&cursor[e], 1);
    int gidx = offsets[e] + pos;
    pair_tok[gidx] = t;
    pair_wt[gidx] = route_w[2*t + k];
  }
}

// ---------------- stage A: h = silu(x@w1) * (x@w3), grouped by expert ----------------
// grid: (mtile<=64, ftile=32, expert=8); block 256 (4 waves, 2x2 over 128x128 tile)
__global__ __launch_bounds__(256, 2) void k_ffn1(
    const unsigned short* __restrict__ xb,
    const unsigned short* __restrict__ w1t,   // [e][f][d] bf16
    const unsigned short* __restrict__ w3t,
    const int* __restrict__ counts, const int* __restrict__ offsets,
    const int* __restrict__ pair_tok,
    unsigned short* __restrict__ h)           // [pair][f] bf16
{
  int e = blockIdx.z;
  int cnt = counts[e];
  int m0 = blockIdx.x * 128;
  if(m0 >= cnt) return;
  int off = offsets[e];
  int n0 = blockIdx.y * 128;

  __shared__ short As[128*32];
  __shared__ short B1s[128*32];
  __shared__ short B3s[128*32];
  __shared__ int stok[128];

  int tid = threadIdx.x;
  if(tid < 128){
    int pr = m0 + tid;
    stok[tid] = pair_tok[off + imin(pr, cnt - 1)];  // clamp tail rows to a valid token
  }
  __syncthreads();

  int wave = tid >> 6, lane = tid & 63;
  int rr  = wave * 32 + (lane >> 2);        // row within 128-tile for staging instr 0
  int g16 = (lane & 3) * 16;                // 16B granule within the 64B row-slice

  const char* a0 = (const char*)xb + (size_t)stok[rr]      * (DMODEL*2) + g16;
  const char* a1 = (const char*)xb + (size_t)stok[rr + 16] * (DMODEL*2) + g16;
  const char* b1base = (const char*)w1t + ((size_t)e * FDIM + n0) * (DMODEL*2);
  const char* b3base = (const char*)w3t + ((size_t)e * FDIM + n0) * (DMODEL*2);
  const char* b1_0 = b1base + (size_t)rr * (DMODEL*2) + g16;
  const char* b1_1 = b1_0 + (size_t)16 * (DMODEL*2);
  const char* b3_0 = b3base + (size_t)rr * (DMODEL*2) + g16;
  const char* b3_1 = b3_0 + (size_t)16 * (DMODEL*2);

  short* adst0  = As  + wave*32*32;  short* adst1  = adst0  + 16*32;
  short* b1dst0 = B1s + wave*32*32;  short* b1dst1 = b1dst0 + 16*32;
  short* b3dst0 = B3s + wave*32*32;  short* b3dst1 = b3dst0 + 16*32;

  f4v zero = {0.f, 0.f, 0.f, 0.f};
  f4v acc1[4][4], acc3[4][4];
  #pragma unroll
  for(int i = 0; i < 4; i++)
    #pragma unroll
    for(int j = 0; j < 4; j++){ acc1[i][j] = zero; acc3[i][j] = zero; }

  int wm = wave & 1, wn = wave >> 1;
  int lm = lane & 15, quad = lane >> 4;

  for(int kt = 0; kt < DMODEL; kt += 32){
    int kb = kt * 2;
    __syncthreads();                          // previous fragments consumed
    GLDS16(a0  + kb, adst0);  GLDS16(a1  + kb, adst1);
    GLDS16(b1_0 + kb, b1dst0); GLDS16(b1_1 + kb, b1dst1);
    GLDS16(b3_0 + kb, b3dst0); GLDS16(b3_1 + kb, b3dst1);
    __syncthreads();                          // staging drained (vmcnt before barrier)

    s8v af[4], b1f[4], b3f[4];
    #pragma unroll
    for(int mi = 0; mi < 4; mi++)
      af[mi] = *(const s8v*)(As + (wm*64 + mi*16 + lm)*32 + quad*8);
    #pragma unroll
    for(int ni = 0; ni < 4; ni++){
      b1f[ni] = *(const s8v*)(B1s + (wn*64 + ni*16 + lm)*32 + quad*8);
      b3f[ni] = *(const s8v*)(B3s + (wn*64 + ni*16 + lm)*32 + quad*8);
    }
    #pragma unroll
    for(int mi = 0; mi < 4; mi++)
      #pragma unroll
      for(int ni = 0; ni < 4; ni++){
        acc1[mi][ni] = mfma16(af[mi], b1f[ni], acc1[mi][ni]);
        acc3[mi][ni] = mfma16(af[mi], b3f[ni], acc3[mi][ni]);
      }
  }

  // epilogue: SwiGLU, store bf16 h. C/D layout: col=lane&15, row=quad*4+reg
  #pragma unroll
  for(int mi = 0; mi < 4; mi++){
    int prb = m0 + wm*64 + mi*16 + quad*4;
    #pragma unroll
    for(int i = 0; i < 4; i++){
      int pr = prb + i;
      if(pr < cnt){
        size_t hrow = (size_t)(off + pr) * FDIM + n0 + wn*64 + lm;
        #pragma unroll
        for(int ni = 0; ni < 4; ni++){
          float p = acc1[mi][ni][i];
          float q = acc3[mi][ni][i];
          float hv = (p / (1.f + __expf(-p))) * q;   // silu(p)*q
          h[hrow + ni*16] = f2b(hv);
        }
      }
    }
  }
}

// ---------------- stage B: out[tok] += wt * (h @ w2), grouped by expert ----------------
// grid: (mtile<=64, dtile=8, expert=8)
__global__ __launch_bounds__(256, 2) void k_ffn2(
    const unsigned short* __restrict__ h,     // [pair][f] bf16
    const unsigned short* __restrict__ w2t,   // [e][d][f] bf16
    const int* __restrict__ counts, const int* __restrict__ offsets,
    const int* __restrict__ pair_tok, const float* __restrict__ pair_wt,
    float* __restrict__ out)
{
  int e = blockIdx.z;
  int cnt = counts[e];
  int m0 = blockIdx.x * 128;
  if(m0 >= cnt) return;
  int off = offsets[e];
  int n0 = blockIdx.y * 128;

  __shared__ short As[128*32];
  __shared__ short Bs[128*32];

  int tid = threadIdx.x, wave = tid >> 6, lane = tid & 63;
  int rr  = wave * 32 + (lane >> 2);
  int g16 = (lane & 3) * 16;

  int pr0 = imin(m0 + rr,      cnt - 1);
  int pr1 = imin(m0 + rr + 16, cnt - 1);
  const char* a0 = (const char*)h + (size_t)(off + pr0) * (FDIM*2) + g16;
  const char* a1 = (const char*)h + (size_t)(off + pr1) * (FDIM*2) + g16;
  const char* bbase = (const char*)w2t + ((size_t)e * DMODEL + n0) * (FDIM*2);
  const char* b0 = bbase + (size_t)rr * (FDIM*2) + g16;
  const char* b1p = b0 + (size_t)16 * (FDIM*2);

  short* adst0 = As + wave*32*32;  short* adst1 = adst0 + 16*32;
  short* bdst0 = Bs + wave*32*32;  short* bdst1 = bdst0 + 16*32;

  f4v zero = {0.f, 0.f, 0.f, 0.f};
  f4v acc[4][4];
  #pragma unroll
  for(int i = 0; i < 4; i++)
    #pragma unroll
    for(int j = 0; j < 4; j++) acc[i][j] = zero;

  int wm = wave & 1, wn = wave >> 1;
  int lm = lane & 15, quad = lane >> 4;

  for(int kt = 0; kt < FDIM; kt += 32){
    int kb = kt * 2;
    __syncthreads();
    GLDS16(a0 + kb, adst0);  GLDS16(a1 + kb, adst1);
    GLDS16(b0 + kb, bdst0);  GLDS16(b1p + kb, bdst1);
    __syncthreads();

    s8v af[4], bf[4];
    #pragma unroll
    for(int mi = 0; mi < 4; mi++)
      af[mi] = *(const s8v*)(As + (wm*64 + mi*16 + lm)*32 + quad*8);
    #pragma unroll
    for(int ni = 0; ni < 4; ni++)
      bf[ni] = *(const s8v*)(Bs + (wn*64 + ni*16 + lm)*32 + quad*8);
    #pragma unroll
    for(int mi = 0; mi < 4; mi++)
      #pragma unroll
      for(int ni = 0; ni < 4; ni++)
        acc[mi][ni] = mfma16(af[mi], bf[ni], acc[mi][ni]);
  }

  // epilogue: scale by gate weight, atomicAdd into out (2 contributions/token, exact)
  #pragma unroll
  for(int mi = 0; mi < 4; mi++){
    int prb = m0 + wm*64 + mi*16 + quad*4;
    #pragma unroll
    for(int i = 0; i < 4; i++){
      int pr = prb + i;
      if(pr < cnt){
        int gp = off + pr;
        int tok = pair_tok[gp];
        float wt = pair_wt[gp];
        float* orow = out + (size_t)tok * DMODEL + n0 + wn*64 + lm;
        #pragma unroll
        for(int ni = 0; ni < 4; ni++)
          atomicAdd(orow + ni*16, acc[mi][ni][i] * wt);
      }
    }
  }
}

extern "C" void kernel_launch(void* const* d_in, const int* in_sizes, int n_in,
                              void* d_out, int out_size, void* d_ws, size_t ws_size,
                              hipStream_t stream){
  const float* x  = (const float*)d_in[0];
  const float* gw = (const float*)d_in[1];
  const float* w1 = (const float*)d_in[2];
  const float* w3 = (const float*)d_in[3];
  const float* w2 = (const float*)d_in[4];
  float* out = (float*)d_out;

  char* ws = (char*)d_ws;
  size_t o = 0;
  auto alloc = [&](size_t b){ size_t r = o; o += (b + 255) & ~(size_t)255; return r; };
  unsigned short* xb  = (unsigned short*)(ws + alloc((size_t)NTOK * DMODEL * 2));
  unsigned short* w1t = (unsigned short*)(ws + alloc((size_t)NEXP * DMODEL * FDIM * 2));
  unsigned short* w3t = (unsigned short*)(ws + alloc((size_t)NEXP * DMODEL * FDIM * 2));
  unsigned short* w2t = (unsigned short*)(ws + alloc((size_t)NEXP * DMODEL * FDIM * 2));
  unsigned short* h   = (unsigned short*)(ws + alloc((size_t)2 * NTOK * FDIM * 2));
  int*   route_e  = (int*)  (ws + alloc(2 * NTOK * 4));
  float* route_w  = (float*)(ws + alloc(2 * NTOK * 4));
  int*   counts   = (int*)  (ws + alloc(256));
  int*   offsets  = (int*)  (ws + alloc(256));
  int*   cursor   = (int*)  (ws + alloc(256));
  int*   pair_tok = (int*)  (ws + alloc(2 * NTOK * 4));
  float* pair_wt  = (float*)(ws + alloc(2 * NTOK * 4));

  hipMemsetAsync(counts, 0, 256, stream);
  hipMemsetAsync(out, 0, (size_t)out_size * 4, stream);

  // bf16 conversions / weight transposes to [n][k] layout
  k_cvt<<<2048, 256, 0, stream>>>((const float4*)x, (ushort4*)xb, NTOK * DMODEL / 4);
  k_tr<<<dim3(FDIM/32, DMODEL/32, NEXP), 256, 0, stream>>>(w1, w1t, DMODEL, FDIM);
  k_tr<<<dim3(FDIM/32, DMODEL/32, NEXP), 256, 0, stream>>>(w3, w3t, DMODEL, FDIM);
  k_tr<<<dim3(DMODEL/32, FDIM/32, NEXP), 256, 0, stream>>>(w2, w2t, FDIM, DMODEL);

  // routing
  k_router<<<NTOK/4, 256, 0, stream>>>(x, gw, route_e, route_w, counts);
  k_scan<<<1, 64, 0, stream>>>(counts, offsets, cursor);
  k_fill<<<NTOK/256, 256, 0, stream>>>(route_e, route_w, offsets, cursor, pair_tok, pair_wt);

  // grouped GEMMs (worst-case grid; blocks past cnt exit early)
  k_ffn1<<<dim3(64, FDIM/128, NEXP), 256, 0, stream>>>(xb, w1t, w3t, counts, offsets, pair_tok, h);
  k_ffn2<<<dim3(64, DMODEL/128, NEXP), 256, 0, stream>>>(h, w2t, counts, offsets, pair_tok, pair_wt, out);
}

// Round 2
// 1607.037 us; speedup vs baseline: 1.0188x; 1.0188x over previous
//
#include <hip/hip_runtime.h>
#include <hip/hip_bf16.h>

// MoE FFN: B=4 T=2048 D=1024 F=4096 E=8 top-2, fp32 in/out.
// Strategy: fp32 router -> expert buckets -> bf16 MFMA grouped GEMMs
// (stage A: x@w1, x@w3 fused SwiGLU -> h; stage B: h@w2 -> atomicAdd out).
// R2: XOR-swizzled LDS granule placement kills the 4-8 way bank conflicts
// (SQ_LDS_BANK_CONFLICT was 2.6e7 per ffn1 dispatch with naive [row][64B] layout).

#define NTOK 8192
#define DMODEL 1024
#define FDIM 4096
#define NEXP 8

typedef __attribute__((ext_vector_type(8))) short s8v;   // 8 x bf16 (4 VGPR)
typedef __attribute__((ext_vector_type(4))) float f4v;   // MFMA accumulator

__device__ __forceinline__ int imin(int a, int b){ return a < b ? a : b; }

// fp32 -> bf16 round-to-nearest-even
__device__ __forceinline__ unsigned short f2b(float f){
  union { float f; unsigned u; } v; v.f = f;
  unsigned r = v.u + 0x7fffu + ((v.u >> 16) & 1u);
  return (unsigned short)(r >> 16);
}

__device__ __forceinline__ f4v mfma16(s8v a, s8v b, f4v c){
  return __builtin_amdgcn_mfma_f32_16x16x32_bf16(a, b, c, 0, 0, 0);
}

// async global->LDS, 16B/lane; LDS dest = wave-uniform base + lane*16
#define GLDS16(gp, lp) __builtin_amdgcn_global_load_lds(                      \
    (const __attribute__((address_space(1))) void*)(gp),                      \
    (__attribute__((address_space(3))) void*)(lp), 16, 0, 0)

// LDS swizzle: source 16B-granule g of row r lives at LDS position g ^ ((r>>1)&3).
// Staging lane L (row r=L>>2, LDS pos L&3) therefore FETCHES source granule
// (L&3)^((L>>3)&3); fragment reads at row lm, granule quad use LDS position
// quad^((lm>>1)&3). Row-base offsets are multiples of 16 so they drop out.

// ---------------- fp32 -> bf16 elementwise (x) ----------------
__global__ void k_cvt(const float4* __restrict__ in, ushort4* __restrict__ out, int n4){
  int i = blockIdx.x * blockDim.x + threadIdx.x;
  int st = gridDim.x * blockDim.x;
  for(; i < n4; i += st){
    float4 v = in[i];
    ushort4 o;
    o.x = f2b(v.x); o.y = f2b(v.y); o.z = f2b(v.z); o.w = f2b(v.w);
    out[i] = o;
  }
}

// ---------------- fp32 [e][R][C] -> bf16 [e][C][R] transpose ----------------
__global__ void k_tr(const float* __restrict__ in, unsigned short* __restrict__ out,
                     int R, int C){
  __shared__ float tile[32][33];
  const float* src = in + (size_t)blockIdx.z * R * C;
  unsigned short* dst = out + (size_t)blockIdx.z * R * C;
  int bx = blockIdx.x * 32, by = blockIdx.y * 32;
  int tx = threadIdx.x & 31, ty = threadIdx.x >> 5;
  #pragma unroll
  for(int i = 0; i < 32; i += 8)
    tile[ty + i][tx] = src[(size_t)(by + ty + i) * C + bx + tx];
  __syncthreads();
  #pragma unroll
  for(int i = 0; i < 32; i += 8)
    dst[(size_t)(bx + ty + i) * R + by + tx] = f2b(tile[tx][ty + i]);
}

// ---------------- router: fp32 logits -> softmax -> top2 -> renorm ----------------
__global__ void k_router(const float* __restrict__ x, const float* __restrict__ gw,
                         int* __restrict__ route_e, float* __restrict__ route_w,
                         int* __restrict__ counts){
  int lane = threadIdx.x & 63;
  int t = blockIdx.x * 4 + (threadIdx.x >> 6);   // one wave per token
  const float* xr = x + (size_t)t * DMODEL;
  float acc[NEXP];
  #pragma unroll
  for(int e = 0; e < NEXP; e++) acc[e] = 0.f;
  for(int d = lane; d < DMODEL; d += 64){
    float xv = xr[d];
    const float* g = gw + d * NEXP;
    #pragma unroll
    for(int e = 0; e < NEXP; e++) acc[e] += xv * g[e];
  }
  #pragma unroll
  for(int off = 32; off > 0; off >>= 1){
    #pragma unroll
    for(int e = 0; e < NEXP; e++) acc[e] += __shfl_down(acc[e], off, 64);
  }
  if(lane == 0){
    float mx = acc[0];
    #pragma unroll
    for(int e = 1; e < NEXP; e++) mx = fmaxf(mx, acc[e]);
    float p[NEXP];
    #pragma unroll
    for(int e = 0; e < NEXP; e++) p[e] = expf(acc[e] - mx);
    int i0 = 0;
    #pragma unroll
    for(int e = 1; e < NEXP; e++) if(p[e] > p[i0]) i0 = e;     // first-max (jax tie rule)
    int i1 = (i0 == 0) ? 1 : 0;
    #pragma unroll
    for(int e = 0; e < NEXP; e++) if(e != i0 && p[e] > p[i1]) i1 = e;
    float inv = 1.f / (p[i0] + p[i1]);           // softmax denom cancels in ratio
    route_e[2*t]   = i0; route_e[2*t+1] = i1;
    route_w[2*t]   = p[i0] * inv;
    route_w[2*t+1] = p[i1] * inv;
    atomicAdd(&counts[i0], 1); atomicAdd(&counts[i1], 1);
  }
}

__global__ void k_scan(const int* __restrict__ counts, int* __restrict__ offsets,
                       int* __restrict__ cursor){
  if(threadIdx.x == 0){
    int o = 0;
    for(int e = 0; e < NEXP; e++){ offsets[e] = o; o += counts[e]; cursor[e] = 0; }
    offsets[NEXP] = o;
  }
}

__global__ void k_fill(const int* __restrict__ route_e, const float* __restrict__ route_w,
                       const int* __restrict__ offsets, int* __restrict__ cursor,
                       int* __restrict__ pair_tok, float* __restrict__ pair_wt){
  int t = blockIdx.x * blockDim.x + threadIdx.x;
  if(t >= NTOK) return;
  #pragma unroll
  for(int k = 0; k < 2; k++){
    int e = route_e[2*t + k];
    int pos = atomicAdd(&cursor[e], 1);
    int gidx = offsets[e] + pos;
    pair_tok[gidx] = t;
    pair_wt[gidx] = route_w[2*t + k];
  }
}

// ---------------- stage A: h = silu(x@w1) * (x@w3), grouped by expert ----------------
// grid: (mtile<=64, ftile=32, expert=8); block 256 (4 waves, 2x2 over 128x128 tile)
__global__ __launch_bounds__(256, 2) void k_ffn1(
    const unsigned short* __restrict__ xb,
    const unsigned short* __restrict__ w1t,   // [e][f][d] bf16
    const unsigned short* __restrict__ w3t,
    const int* __restrict__ counts, const int* __restrict__ offsets,
    const int* __restrict__ pair_tok,
    unsigned short* __restrict__ h)           // [pair][f] bf16
{
  int e = blockIdx.z;
  int cnt = counts[e];
  int m0 = blockIdx.x * 128;
  if(m0 >= cnt) return;
  int off = offsets[e];
  int n0 = blockIdx.y * 128;

  __shared__ short As[128*32];
  __shared__ short B1s[128*32];
  __shared__ short B3s[128*32];
  __shared__ int stok[128];

  int tid = threadIdx.x;
  if(tid < 128){
    int pr = m0 + tid;
    stok[tid] = pair_tok[off + imin(pr, cnt - 1)];  // clamp tail rows to a valid token
  }
  __syncthreads();

  int wave = tid >> 6, lane = tid & 63;
  int rr  = wave * 32 + (lane >> 2);        // row within 128-tile for staging instr 0
  // swizzled source granule within the row's 64B slice (see swizzle note above)
  int g16 = (((lane & 3) ^ ((lane >> 3) & 3))) * 16;

  const char* a0 = (const char*)xb + (size_t)stok[rr]      * (DMODEL*2) + g16;
  const char* a1 = (const char*)xb + (size_t)stok[rr + 16] * (DMODEL*2) + g16;
  const char* b1base = (const char*)w1t + ((size_t)e * FDIM + n0) * (DMODEL*2);
  const char* b3base = (const char*)w3t + ((size_t)e * FDIM + n0) * (DMODEL*2);
  const char* b1_0 = b1base + (size_t)rr * (DMODEL*2) + g16;
  const char* b1_1 = b1_0 + (size_t)16 * (DMODEL*2);
  const char* b3_0 = b3base + (size_t)rr * (DMODEL*2) + g16;
  const char* b3_1 = b3_0 + (size_t)16 * (DMODEL*2);

  short* adst0  = As  + wave*32*32;  short* adst1  = adst0  + 16*32;
  short* b1dst0 = B1s + wave*32*32;  short* b1dst1 = b1dst0 + 16*32;
  short* b3dst0 = B3s + wave*32*32;  short* b3dst1 = b3dst0 + 16*32;

  f4v zero = {0.f, 0.f, 0.f, 0.f};
  f4v acc1[4][4], acc3[4][4];
  #pragma unroll
  for(int i = 0; i < 4; i++)
    #pragma unroll
    for(int j = 0; j < 4; j++){ acc1[i][j] = zero; acc3[i][j] = zero; }

  int wm = wave & 1, wn = wave >> 1;
  int lm = lane & 15, quad = lane >> 4;
  int rp = (quad ^ ((lm >> 1) & 3)) * 8;    // swizzled LDS position of granule `quad`

  for(int kt = 0; kt < DMODEL; kt += 32){
    int kb = kt * 2;
    __syncthreads();                          // previous fragments consumed
    GLDS16(a0  + kb, adst0);  GLDS16(a1  + kb, adst1);
    GLDS16(b1_0 + kb, b1dst0); GLDS16(b1_1 + kb, b1dst1);
    GLDS16(b3_0 + kb, b3dst0); GLDS16(b3_1 + kb, b3dst1);
    __syncthreads();                          // staging drained (vmcnt before barrier)

    s8v af[4], b1f[4], b3f[4];
    #pragma unroll
    for(int mi = 0; mi < 4; mi++)
      af[mi] = *(const s8v*)(As + (wm*64 + mi*16 + lm)*32 + rp);
    #pragma unroll
    for(int ni = 0; ni < 4; ni++){
      b1f[ni] = *(const s8v*)(B1s + (wn*64 + ni*16 + lm)*32 + rp);
      b3f[ni] = *(const s8v*)(B3s + (wn*64 + ni*16 + lm)*32 + rp);
    }
    #pragma unroll
    for(int mi = 0; mi < 4; mi++)
      #pragma unroll
      for(int ni = 0; ni < 4; ni++){
        acc1[mi][ni] = mfma16(af[mi], b1f[ni], acc1[mi][ni]);
        acc3[mi][ni] = mfma16(af[mi], b3f[ni], acc3[mi][ni]);
      }
  }

  // epilogue: SwiGLU, store bf16 h. C/D layout: col=lane&15, row=quad*4+reg
  #pragma unroll
  for(int mi = 0; mi < 4; mi++){
    int prb = m0 + wm*64 + mi*16 + quad*4;
    #pragma unroll
    for(int i = 0; i < 4; i++){
      int pr = prb + i;
      if(pr < cnt){
        size_t hrow = (size_t)(off + pr) * FDIM + n0 + wn*64 + lm;
        #pragma unroll
        for(int ni = 0; ni < 4; ni++){
          float p = acc1[mi][ni][i];
          float q = acc3[mi][ni][i];
          float hv = (p / (1.f + __expf(-p))) * q;   // silu(p)*q
          h[hrow + ni*16] = f2b(hv);
        }
      }
    }
  }
}

// ---------------- stage B: out[tok] += wt * (h @ w2), grouped by expert ----------------
// grid: (mtile<=64, dtile=8, expert=8)
__global__ __launch_bounds__(256, 2) void k_ffn2(
    const unsigned short* __restrict__ h,     // [pair][f] bf16
    const unsigned short* __restrict__ w2t,   // [e][d][f] bf16
    const int* __restrict__ counts, const int* __restrict__ offsets,
    const int* __restrict__ pair_tok, const float* __restrict__ pair_wt,
    float* __restrict__ out)
{
  int e = blockIdx.z;
  int cnt = counts[e];
  int m0 = blockIdx.x * 128;
  if(m0 >= cnt) return;
  int off = offsets[e];
  int n0 = blockIdx.y * 128;

  __shared__ short As[128*32];
  __shared__ short Bs[128*32];

  int tid = threadIdx.x, wave = tid >> 6, lane = tid & 63;
  int rr  = wave * 32 + (lane >> 2);
  int g16 = (((lane & 3) ^ ((lane >> 3) & 3))) * 16;   // swizzled source granule

  int pr0 = imin(m0 + rr,      cnt - 1);
  int pr1 = imin(m0 + rr + 16, cnt - 1);
  const char* a0 = (const char*)h + (size_t)(off + pr0) * (FDIM*2) + g16;
  const char* a1 = (const char*)h + (size_t)(off + pr1) * (FDIM*2) + g16;
  const char* bbase = (const char*)w2t + ((size_t)e * DMODEL + n0) * (FDIM*2);
  const char* b0 = bbase + (size_t)rr * (FDIM*2) + g16;
  const char* b1p = b0 + (size_t)16 * (FDIM*2);

  short* adst0 = As + wave*32*32;  short* adst1 = adst0 + 16*32;
  short* bdst0 = Bs + wave*32*32;  short* bdst1 = bdst0 + 16*32;

  f4v zero = {0.f, 0.f, 0.f, 0.f};
  f4v acc[4][4];
  #pragma unroll
  for(int i = 0; i < 4; i++)
    #pragma unroll
    for(int j = 0; j < 4; j++) acc[i][j] = zero;

  int wm = wave & 1, wn = wave >> 1;
  int lm = lane & 15, quad = lane >> 4;
  int rp = (quad ^ ((lm >> 1) & 3)) * 8;    // swizzled LDS position of granule `quad`

  for(int kt = 0; kt < FDIM; kt += 32){
    int kb = kt * 2;
    __syncthreads();
    GLDS16(a0 + kb, adst0);  GLDS16(a1 + kb, adst1);
    GLDS16(b0 + kb, bdst0);  GLDS16(b1p + kb, bdst1);
    __syncthreads();

    s8v af[4], bf[4];
    #pragma unroll
    for(int mi = 0; mi < 4; mi++)
      af[mi] = *(const s8v*)(As + (wm*64 + mi*16 + lm)*32 + rp);
    #pragma unroll
    for(int ni = 0; ni < 4; ni++)
      bf[ni] = *(const s8v*)(Bs + (wn*64 + ni*16 + lm)*32 + rp);
    #pragma unroll
    for(int mi = 0; mi < 4; mi++)
      #pragma unroll
      for(int ni = 0; ni < 4; ni++)
        acc[mi][ni] = mfma16(af[mi], bf[ni], acc[mi][ni]);
  }

  // epilogue: scale by gate weight, atomicAdd into out (2 contributions/token, exact)
  #pragma unroll
  for(int mi = 0; mi < 4; mi++){
    int prb = m0 + wm*64 + mi*16 + quad*4;
    #pragma unroll
    for(int i = 0; i < 4; i++){
      int pr = prb + i;
      if(pr < cnt){
        int gp = off + pr;
        int tok = pair_tok[gp];
        float wt = pair_wt[gp];
        float* orow = out + (size_t)tok * DMODEL + n0 + wn*64 + lm;
        #pragma unroll
        for(int ni = 0; ni < 4; ni++)
          atomicAdd(orow + ni*16, acc[mi][ni][i] * wt);
      }
    }
  }
}

extern "C" void kernel_launch(void* const* d_in, const int* in_sizes, int n_in,
                              void* d_out, int out_size, void* d_ws, size_t ws_size,
                              hipStream_t stream){
  const float* x  = (const float*)d_in[0];
  const float* gw = (const float*)d_in[1];
  const float* w1 = (const float*)d_in[2];
  const float* w3 = (const float*)d_in[3];
  const float* w2 = (const float*)d_in[4];
  float* out = (float*)d_out;

  char* ws = (char*)d_ws;
  size_t o = 0;
  auto alloc = [&](size_t b){ size_t r = o; o += (b + 255) & ~(size_t)255; return r; };
  unsigned short* xb  = (unsigned short*)(ws + alloc((size_t)NTOK * DMODEL * 2));
  unsigned short* w1t = (unsigned short*)(ws + alloc((size_t)NEXP * DMODEL * FDIM * 2));
  unsigned short* w3t = (unsigned short*)(ws + alloc((size_t)NEXP * DMODEL * FDIM * 2));
  unsigned short* w2t = (unsigned short*)(ws + alloc((size_t)NEXP * DMODEL * FDIM * 2));
  unsigned short* h   = (unsigned short*)(ws + alloc((size_t)2 * NTOK * FDIM * 2));
  int*   route_e  = (int*)  (ws + alloc(2 * NTOK * 4));
  float* route_w  = (float*)(ws + alloc(2 * NTOK * 4));
  int*   counts   = (int*)  (ws + alloc(256));
  int*   offsets  = (int*)  (ws + alloc(256));
  int*   cursor   = (int*)  (ws + alloc(256));
  int*   pair_tok = (int*)  (ws + alloc(2 * NTOK * 4));
  float* pair_wt  = (float*)(ws + alloc(2 * NTOK * 4));

  hipMemsetAsync(counts, 0, 256, stream);
  hipMemsetAsync(out, 0, (size_t)out_size * 4, stream);

  // bf16 conversions / weight transposes to [n][k] layout
  k_cvt<<<2048, 256, 0, stream>>>((const float4*)x, (ushort4*)xb, NTOK * DMODEL / 4);
  k_tr<<<dim3(FDIM/32, DMODEL/32, NEXP), 256, 0, stream>>>(w1, w1t, DMODEL, FDIM);
  k_tr<<<dim3(FDIM/32, DMODEL/32, NEXP), 256, 0, stream>>>(w3, w3t, DMODEL, FDIM);
  k_tr<<<dim3(DMODEL/32, FDIM/32, NEXP), 256, 0, stream>>>(w2, w2t, FDIM, DMODEL);

  // routing
  k_router<<<NTOK/4, 256, 0, stream>>>(x, gw, route_e, route_w, counts);
  k_scan<<<1, 64, 0, stream>>>(counts, offsets, cursor);
  k_fill<<<NTOK/256, 256, 0, stream>>>(route_e, route_w, offsets, cursor, pair_tok, pair_wt);

  // grouped GEMMs (worst-case grid; blocks past cnt exit early)
  k_ffn1<<<dim3(64, FDIM/128, NEXP), 256, 0, stream>>>(xb, w1t, w3t, counts, offsets, pair_tok, h);
  k_ffn2<<<dim3(64, DMODEL/128, NEXP), 256, 0, stream>>>(h, w2t, counts, offsets, pair_tok, pair_wt, out);
}